// Round 1
// baseline (495.134 us; speedup 1.0000x reference)
//
#include <hip/hip_runtime.h>
#include <hip/hip_bf16.h>

typedef __hip_bfloat16 bf16;
typedef __attribute__((ext_vector_type(8))) __bf16 bf16x8;
typedef __attribute__((ext_vector_type(4))) float f32x4;
typedef __attribute__((ext_vector_type(8))) short s16x8;

#define B_    8
#define S_    1024
#define H_    16
#define D_    128
#define HID_  2048
#define NQKV_ 2304
#define T_    8192

__device__ __forceinline__ void gload_lds16(const void* g, void* l) {
  __builtin_amdgcn_global_load_lds((const __attribute__((address_space(1))) void*)g,
                                   (__attribute__((address_space(3))) void*)l, 16, 0, 0);
}

// ---------------- cast fp32 -> bf16, 8 elems/thread ----------------
__global__ void cast_bf16_kernel(const float* __restrict__ src, bf16* __restrict__ dst, int n8) {
  const int i = blockIdx.x * 256 + threadIdx.x;
  if (i >= n8) return;
  const float4 a = ((const float4*)src)[2 * i];
  const float4 b = ((const float4*)src)[2 * i + 1];
  s16x8 o;
  o[0] = (short)__bfloat16_as_ushort(__float2bfloat16(a.x));
  o[1] = (short)__bfloat16_as_ushort(__float2bfloat16(a.y));
  o[2] = (short)__bfloat16_as_ushort(__float2bfloat16(a.z));
  o[3] = (short)__bfloat16_as_ushort(__float2bfloat16(a.w));
  o[4] = (short)__bfloat16_as_ushort(__float2bfloat16(b.x));
  o[5] = (short)__bfloat16_as_ushort(__float2bfloat16(b.y));
  o[6] = (short)__bfloat16_as_ushort(__float2bfloat16(b.z));
  o[7] = (short)__bfloat16_as_ushort(__float2bfloat16(b.w));
  ((s16x8*)dst)[i] = o;
}

// ------------- transpose + cast: src (R x C) f32 -> dst (C x R) bf16 -------------
__global__ void transpose_cast_kernel(const float* __restrict__ src, bf16* __restrict__ dst,
                                      int R, int C) {
  __shared__ float tile[32][33];
  const int tx = threadIdx.x & 31, ty = threadIdx.x >> 5;
  const int rt = blockIdx.y * 32, ct = blockIdx.x * 32;
#pragma unroll
  for (int k = 0; k < 4; ++k)
    tile[ty + 8 * k][tx] = src[(size_t)(rt + ty + 8 * k) * C + ct + tx];
  __syncthreads();
#pragma unroll
  for (int k = 0; k < 4; ++k)
    dst[(size_t)(ct + ty + 8 * k) * R + rt + tx] = __float2bfloat16(tile[tx][ty + 8 * k]);
}

// ------------- GEMM: A (MxK bf16) * Bt(NxK bf16)^T + bias -> C (MxN) -------------
// 128x128 tile, BK=32, 4 waves (2x2), 16x16x32 MFMA, global_load_lds staging (m97 structure)
template <bool OUT_F32>
__global__ __launch_bounds__(256) void gemm_kernel(const bf16* __restrict__ A,
                                                   const bf16* __restrict__ Bt,
                                                   const float* __restrict__ bias,
                                                   void* __restrict__ Cout,
                                                   int M, int N, int K) {
  __shared__ bf16 As[128 * 32];
  __shared__ bf16 Bs[128 * 32];
  const int tid = threadIdx.x;
  const int lane = tid & 63;
  const int wave = tid >> 6;
  const int bn = blockIdx.x, bm = blockIdx.y;
  const int lrow = lane & 15, lk = lane >> 4;
  const int rbase = (wave >> 1) * 64;
  const int nbase = (wave & 1) * 64;
  f32x4 acc[4][4] = {};

  const int flat0 = wave * 1024 + (lane << 4);
  for (int kt = 0; kt < K; kt += 32) {
#pragma unroll
    for (int c = 0; c < 2; ++c) {
      const int flat = c * 4096 + flat0;
      const int row = flat >> 6;     // 64B per row (32 bf16)
      const int colb = flat & 63;
      gload_lds16((const char*)(A + (size_t)(bm * 128 + row) * K + kt) + colb,
                  (char*)As + c * 4096 + wave * 1024);
      gload_lds16((const char*)(Bt + (size_t)(bn * 128 + row) * K + kt) + colb,
                  (char*)Bs + c * 4096 + wave * 1024);
    }
    __syncthreads();
    bf16x8 af[4], bfr[4];
#pragma unroll
    for (int mi = 0; mi < 4; ++mi)
      af[mi] = *(const bf16x8*)(As + (size_t)(rbase + mi * 16 + lrow) * 32 + lk * 8);
#pragma unroll
    for (int ni = 0; ni < 4; ++ni)
      bfr[ni] = *(const bf16x8*)(Bs + (size_t)(nbase + ni * 16 + lrow) * 32 + lk * 8);
#pragma unroll
    for (int mi = 0; mi < 4; ++mi)
#pragma unroll
      for (int ni = 0; ni < 4; ++ni)
        acc[mi][ni] = __builtin_amdgcn_mfma_f32_16x16x32_bf16(af[mi], bfr[ni], acc[mi][ni], 0, 0, 0);
    __syncthreads();
  }
#pragma unroll
  for (int ni = 0; ni < 4; ++ni) {
    const int col = bn * 128 + nbase + ni * 16 + lrow;
    const float bv = bias[col];
#pragma unroll
    for (int mi = 0; mi < 4; ++mi) {
      const int row0 = bm * 128 + rbase + mi * 16 + lk * 4;
#pragma unroll
      for (int r = 0; r < 4; ++r) {
        const float v = acc[mi][ni][r] + bv;
        if (OUT_F32)
          ((float*)Cout)[(size_t)(row0 + r) * N + col] = v;
        else
          ((bf16*)Cout)[(size_t)(row0 + r) * N + col] = __float2bfloat16(v);
      }
    }
  }
}

// ------------- causal MQA flash attention -------------
// grid (S/64, H, B); 256 threads = 4 waves, each wave owns 16 q-rows.
// LDS: [0,16K) Q then K tile (64x128, XOR-swizzled); [16K,32K) V^T (128x64, swizzled);
//      [32K,40K) per-wave P (16x64, swizzled).
__global__ __launch_bounds__(256) void attn_kernel(const bf16* __restrict__ QKV,
                                                   bf16* __restrict__ aout) {
  const int qt = blockIdx.x;
  const int h = blockIdx.y;
  const int b = blockIdx.z;
  const int tid = threadIdx.x;
  const int lane = tid & 63;
  const int wave = tid >> 6;
  const int lrow = lane & 15, lk = lane >> 4;

  __shared__ char lds[40960];
  char* Vt = lds + 16384;
  char* Ps = lds + 32768 + wave * 2048;

  // stage Q (swizzled)
#pragma unroll
  for (int pass = 0; pass < 4; ++pass) {
    const int idx = (pass * 256 + tid) * 8;
    const int r = idx >> 7, c = idx & 127;
    const s16x8 v = *(const s16x8*)(QKV + (size_t)(b * S_ + qt * 64 + r) * NQKV_ + h * D_ + c);
    const int byte = (r * 256 + c * 2) ^ ((r & 7) << 4);
    *(s16x8*)(lds + byte) = v;
  }
  __syncthreads();
  bf16x8 qf[4];
  {
    const int row = wave * 16 + lrow;
#pragma unroll
    for (int kk = 0; kk < 4; ++kk) {
      const int byte = row * 256 + ((kk * 64 + lk * 16) ^ ((row & 7) << 4));
      qf[kk] = *(const bf16x8*)(lds + byte);
    }
  }

  float mrun[4], lrun[4];
  f32x4 Oacc[8] = {};
#pragma unroll
  for (int r = 0; r < 4; ++r) { mrun[r] = -1e30f; lrun[r] = 0.f; }
  const float scale = 0.08838834764831845f;

  for (int kt = 0; kt <= qt; ++kt) {
    __syncthreads();  // previous iteration's K/V reads (and qf reads) done
#pragma unroll
    for (int pass = 0; pass < 4; ++pass) {
      const int idx = (pass * 256 + tid) * 8;
      const int r = idx >> 7, c = idx & 127;
      const size_t gbase = (size_t)(b * S_ + kt * 64 + r) * NQKV_ + HID_;
      const s16x8 kv8 = *(const s16x8*)(QKV + gbase + c);
      const int byte = (r * 256 + c * 2) ^ ((r & 7) << 4);
      *(s16x8*)(lds + byte) = kv8;
      const s16x8 vv = *(const s16x8*)(QKV + gbase + D_ + c);
#pragma unroll
      for (int j = 0; j < 8; ++j) {
        const int d = c + j;
        const int vb = d * 128 + ((r * 2) ^ (((d >> 3) & 7) << 4));
        *(short*)(Vt + vb) = vv[j];
      }
    }
    __syncthreads();

    // QK^T: A = Q rows, B = K^T (16 MFMAs)
    f32x4 sc[4];
#pragma unroll
    for (int cf = 0; cf < 4; ++cf) {
      f32x4 s = {0.f, 0.f, 0.f, 0.f};
      const int row = cf * 16 + lrow;
#pragma unroll
      for (int kk = 0; kk < 4; ++kk) {
        const int byte = row * 256 + ((kk * 64 + lk * 16) ^ ((row & 7) << 4));
        const bf16x8 kf = *(const bf16x8*)(lds + byte);
        s = __builtin_amdgcn_mfma_f32_16x16x32_bf16(qf[kk], kf, s, 0, 0, 0);
      }
      sc[cf] = s;
    }

    const bool diag = (kt == qt);
#pragma unroll
    for (int cf = 0; cf < 4; ++cf)
#pragma unroll
      for (int r = 0; r < 4; ++r) {
        float v = sc[cf][r] * scale;
        if (diag && (cf * 16 + lrow > wave * 16 + lk * 4 + r)) v = -1e30f;
        sc[cf][r] = v;
      }

    // online softmax (wave-parallel: shfl over 16-lane column groups)
    float corr[4];
#pragma unroll
    for (int r = 0; r < 4; ++r) {
      float mv = fmaxf(fmaxf(sc[0][r], sc[1][r]), fmaxf(sc[2][r], sc[3][r]));
#pragma unroll
      for (int xm = 1; xm < 16; xm <<= 1) mv = fmaxf(mv, __shfl_xor(mv, xm, 64));
      const float mn = fmaxf(mrun[r], mv);
      corr[r] = __expf(mrun[r] - mn);
      mrun[r] = mn;
    }
    float rsum[4] = {0.f, 0.f, 0.f, 0.f};
#pragma unroll
    for (int cf = 0; cf < 4; ++cf)
#pragma unroll
      for (int r = 0; r < 4; ++r) {
        const float p = __expf(sc[cf][r] - mrun[r]);
        sc[cf][r] = p;
        rsum[r] += p;
      }
#pragma unroll
    for (int r = 0; r < 4; ++r) {
#pragma unroll
      for (int xm = 1; xm < 16; xm <<= 1) rsum[r] += __shfl_xor(rsum[r], xm, 64);
      lrun[r] = lrun[r] * corr[r] + rsum[r];
    }
#pragma unroll
    for (int f = 0; f < 8; ++f)
#pragma unroll
      for (int r = 0; r < 4; ++r) Oacc[f][r] *= corr[r];

    // P -> LDS (bf16, swizzled), then PV (16 MFMAs)
#pragma unroll
    for (int cf = 0; cf < 4; ++cf)
#pragma unroll
      for (int r = 0; r < 4; ++r) {
        const int prow = lk * 4 + r;
        const int byte = prow * 128 + (((cf * 16 + lrow) * 2) ^ ((prow & 7) << 4));
        *(bf16*)(Ps + byte) = __float2bfloat16(sc[cf][r]);
      }
    asm volatile("s_waitcnt lgkmcnt(0)" ::: "memory");

    bf16x8 pf[2];
#pragma unroll
    for (int ks = 0; ks < 2; ++ks) {
      const int byte = lrow * 128 + ((ks * 64 + lk * 16) ^ ((lrow & 7) << 4));
      pf[ks] = *(const bf16x8*)(Ps + byte);
    }
#pragma unroll
    for (int f = 0; f < 8; ++f) {
      const int d = f * 16 + lrow;
#pragma unroll
      for (int ks = 0; ks < 2; ++ks) {
        const int vb = d * 128 + ((ks * 64 + lk * 16) ^ (((d >> 3) & 7) << 4));
        const bf16x8 vf = *(const bf16x8*)(Vt + vb);
        Oacc[f] = __builtin_amdgcn_mfma_f32_16x16x32_bf16(pf[ks], vf, Oacc[f], 0, 0, 0);
      }
    }
  }

  // epilogue: divide by l, write attn (token-major, col = h*128 + d)
#pragma unroll
  for (int f = 0; f < 8; ++f)
#pragma unroll
    for (int r = 0; r < 4; ++r) {
      const int token = b * S_ + qt * 64 + wave * 16 + lk * 4 + r;
      const int col = h * D_ + f * 16 + lrow;
      aout[(size_t)token * HID_ + col] = __float2bfloat16(Oacc[f][r] / lrun[r]);
    }
}

extern "C" void kernel_launch(void* const* d_in, const int* in_sizes, int n_in,
                              void* d_out, int out_size, void* d_ws, size_t ws_size,
                              hipStream_t stream) {
  const float* hidden = (const float*)d_in[0];
  const float* w_attn = (const float*)d_in[1];
  const float* b_attn = (const float*)d_in[2];
  const float* w_proj = (const float*)d_in[3];
  const float* b_proj = (const float*)d_in[4];

  char* ws = (char*)d_ws;
  char* dob = (char*)d_out;

  // ws layout: [0, 33.5M) Xbf (bf16 hidden), later reused as attn output
  //            [33.5M, 42M) WpT (w_proj^T bf16)
  bf16* Xbf = (bf16*)ws;
  bf16* WpT = (bf16*)(ws + 33554432);
  // d_out used as scratch before the final GEMM writes it:
  //            [0, 37.75M) QKV bf16 ; [37.75M, 47.2M) WaT (w_attn^T bf16)
  bf16* QKV = (bf16*)dob;
  bf16* WaT = (bf16*)(dob + 37748736);

  cast_bf16_kernel<<<(T_ * HID_) / 8 / 256, 256, 0, stream>>>(hidden, Xbf, (T_ * HID_) / 8);
  transpose_cast_kernel<<<dim3(NQKV_ / 32, HID_ / 32), 256, 0, stream>>>(w_attn, WaT, HID_, NQKV_);
  transpose_cast_kernel<<<dim3(HID_ / 32, HID_ / 32), 256, 0, stream>>>(w_proj, WpT, HID_, HID_);

  gemm_kernel<false><<<dim3(NQKV_ / 128, T_ / 128), 256, 0, stream>>>(
      Xbf, WaT, b_attn, QKV, T_, NQKV_, HID_);

  attn_kernel<<<dim3(S_ / 64, H_, B_), 256, 0, stream>>>(QKV, Xbf /* attn out overwrites Xbf */);

  gemm_kernel<true><<<dim3(HID_ / 128, T_ / 128), 256, 0, stream>>>(
      Xbf, WpT, b_proj, (float*)d_out, T_, HID_, HID_);
}

// Round 5
// 462.702 us; speedup vs baseline: 1.0701x; 1.0701x over previous
//
#include <hip/hip_runtime.h>
#include <hip/hip_bf16.h>

typedef __hip_bfloat16 bf16;
typedef __attribute__((ext_vector_type(8))) __bf16 bf16x8;
typedef __attribute__((ext_vector_type(4))) float f32x4;
typedef __attribute__((ext_vector_type(8))) short s16x8;

#define B_    8
#define S_    1024
#define H_    16
#define D_    128
#define HID_  2048
#define NQKV_ 2304
#define T_    8192

__device__ __forceinline__ void gload_lds16(const void* g, void* l) {
  __builtin_amdgcn_global_load_lds((const __attribute__((address_space(1))) void*)g,
                                   (__attribute__((address_space(3))) void*)l, 16, 0, 0);
}

// ---------------- cast fp32 -> bf16, 8 elems/thread ----------------
__global__ void cast_bf16_kernel(const float* __restrict__ src, bf16* __restrict__ dst, int n8) {
  const int i = blockIdx.x * 256 + threadIdx.x;
  if (i >= n8) return;
  const float4 a = ((const float4*)src)[2 * i];
  const float4 b = ((const float4*)src)[2 * i + 1];
  s16x8 o;
  o[0] = (short)__bfloat16_as_ushort(__float2bfloat16(a.x));
  o[1] = (short)__bfloat16_as_ushort(__float2bfloat16(a.y));
  o[2] = (short)__bfloat16_as_ushort(__float2bfloat16(a.z));
  o[3] = (short)__bfloat16_as_ushort(__float2bfloat16(a.w));
  o[4] = (short)__bfloat16_as_ushort(__float2bfloat16(b.x));
  o[5] = (short)__bfloat16_as_ushort(__float2bfloat16(b.y));
  o[6] = (short)__bfloat16_as_ushort(__float2bfloat16(b.z));
  o[7] = (short)__bfloat16_as_ushort(__float2bfloat16(b.w));
  ((s16x8*)dst)[i] = o;
}

// ------------- transpose + cast: src (R x C) f32 -> dst (C x R) bf16 -------------
__global__ void transpose_cast_kernel(const float* __restrict__ src, bf16* __restrict__ dst,
                                      int R, int C) {
  __shared__ float tile[32][33];
  const int tx = threadIdx.x & 31, ty = threadIdx.x >> 5;
  const int rt = blockIdx.y * 32, ct = blockIdx.x * 32;
#pragma unroll
  for (int k = 0; k < 4; ++k)
    tile[ty + 8 * k][tx] = src[(size_t)(rt + ty + 8 * k) * C + ct + tx];
  __syncthreads();
#pragma unroll
  for (int k = 0; k < 4; ++k)
    dst[(size_t)(ct + ty + 8 * k) * R + rt + tx] = __float2bfloat16(tile[tx][ty + 8 * k]);
}

// ------------- V transpose: QKV V-cols -> Vt[b][d][k] bf16 -------------
__global__ void transpose_v_kernel(const bf16* __restrict__ QKV, bf16* __restrict__ Vt) {
  __shared__ short t[64][72];
  const int kt = blockIdx.x, dt = blockIdx.y, b = blockIdx.z;
  const int r = threadIdx.x >> 3;        // 0..31
  const int c8 = (threadIdx.x & 7) * 8;  // 0,8..56
#pragma unroll
  for (int p = 0; p < 2; ++p) {
    const int row = p * 32 + r;
    const s16x8 v = *(const s16x8*)(QKV + (size_t)(b * S_ + kt * 64 + row) * NQKV_ +
                                    HID_ + D_ + dt * 64 + c8);
    *(s16x8*)&t[row][c8] = v;
  }
  __syncthreads();
#pragma unroll
  for (int p = 0; p < 2; ++p) {
    const int drow = p * 32 + r;
    s16x8 o;
#pragma unroll
    for (int j = 0; j < 8; ++j) o[j] = t[c8 + j][drow];
    *(s16x8*)(Vt + (size_t)(b * D_ + dt * 64 + drow) * S_ + kt * 64 + c8) = o;
  }
}

// ------------- GEMM: A (MxK bf16) * Bt(NxK bf16)^T + bias -> C (MxN) -------------
template <bool OUT_F32>
__global__ __launch_bounds__(256) void gemm_kernel(const bf16* __restrict__ A,
                                                   const bf16* __restrict__ Bt,
                                                   const float* __restrict__ bias,
                                                   void* __restrict__ Cout,
                                                   int M, int N, int K) {
  __shared__ bf16 As[128 * 32];
  __shared__ bf16 Bs[128 * 32];
  const int tid = threadIdx.x;
  const int lane = tid & 63;
  const int wave = tid >> 6;
  const int bn = blockIdx.x, bm = blockIdx.y;
  const int lrow = lane & 15, lk = lane >> 4;
  const int rbase = (wave >> 1) * 64;
  const int nbase = (wave & 1) * 64;
  f32x4 acc[4][4] = {};

  const int flat0 = wave * 1024 + (lane << 4);
  for (int kt = 0; kt < K; kt += 32) {
#pragma unroll
    for (int c = 0; c < 2; ++c) {
      const int flat = c * 4096 + flat0;
      const int row = flat >> 6;
      const int colb = flat & 63;
      gload_lds16((const char*)(A + (size_t)(bm * 128 + row) * K + kt) + colb,
                  (char*)As + c * 4096 + wave * 1024);
      gload_lds16((const char*)(Bt + (size_t)(bn * 128 + row) * K + kt) + colb,
                  (char*)Bs + c * 4096 + wave * 1024);
    }
    __syncthreads();
    bf16x8 af[4], bfr[4];
#pragma unroll
    for (int mi = 0; mi < 4; ++mi)
      af[mi] = *(const bf16x8*)(As + (size_t)(rbase + mi * 16 + lrow) * 32 + lk * 8);
#pragma unroll
    for (int ni = 0; ni < 4; ++ni)
      bfr[ni] = *(const bf16x8*)(Bs + (size_t)(nbase + ni * 16 + lrow) * 32 + lk * 8);
#pragma unroll
    for (int mi = 0; mi < 4; ++mi)
#pragma unroll
      for (int ni = 0; ni < 4; ++ni)
        acc[mi][ni] = __builtin_amdgcn_mfma_f32_16x16x32_bf16(af[mi], bfr[ni], acc[mi][ni], 0, 0, 0);
    __syncthreads();
  }
#pragma unroll
  for (int ni = 0; ni < 4; ++ni) {
    const int col = bn * 128 + nbase + ni * 16 + lrow;
    const float bv = bias[col];
#pragma unroll
    for (int mi = 0; mi < 4; ++mi) {
      const int row0 = bm * 128 + rbase + mi * 16 + lk * 4;
#pragma unroll
      for (int r = 0; r < 4; ++r) {
        const float v = acc[mi][ni][r] + bv;
        if (OUT_F32)
          ((float*)Cout)[(size_t)(row0 + r) * N + col] = v;
        else
          ((bf16*)Cout)[(size_t)(row0 + r) * N + col] = __float2bfloat16(v);
      }
    }
  }
}

// ------------- causal MQA flash attention v2 -------------
// grid (S/64 [qt reversed], H, B); 256 threads = 4 waves, each wave owns 16 q-rows.
// LDS: [0,16K) Q then K tile (64 x 256B, XOR-swizzled, gload pre-swizzled source);
//      [16K,32K) Vt tile (128 x 128B, swizzled); [32K,40K) per-wave P (16 x 128B).
__global__ __launch_bounds__(256) void attn_kernel(const bf16* __restrict__ QKV,
                                                   const bf16* __restrict__ Vt,
                                                   bf16* __restrict__ aout) {
  const int qt = gridDim.x - 1 - blockIdx.x;  // long blocks first
  const int h = blockIdx.y;
  const int b = blockIdx.z;
  const int tid = threadIdx.x;
  const int lane = tid & 63;
  const int wave = tid >> 6;
  const int lrow = lane & 15, lk = lane >> 4;

  __shared__ char lds[40960];
  char* Ks = lds;                          // 64 rows x 256B
  char* Vts = lds + 16384;                 // 128 rows x 128B
  char* Ps = lds + 32768 + wave * 2048;    // 16 rows x 128B, per wave

  const char* qkv_b = (const char*)QKV + (size_t)b * S_ * (NQKV_ * 2);
  const char* vt_b = (const char*)Vt + (size_t)b * D_ * S_ * 2;
  const int Xw = wave * 4096;

  // ---- stage Q (64 x 256B) into Ks area, source pre-swizzled ----
#pragma unroll
  for (int o = 0; o < 4; ++o) {
    const int X = Xw + o * 1024 + lane * 16;
    const int r = X >> 8, Y = X & 255;
    const int cb = Y ^ ((r & 7) << 4);
    gload_lds16(qkv_b + (size_t)(qt * 64 + r) * (NQKV_ * 2) + h * 256 + cb,
                Ks + Xw + o * 1024);
  }
  asm volatile("s_waitcnt vmcnt(0)" ::: "memory");
  __builtin_amdgcn_s_barrier();

  bf16x8 qf[4];
  {
    const int row = wave * 16 + lrow;
#pragma unroll
    for (int kk = 0; kk < 4; ++kk)
      qf[kk] = *(const bf16x8*)(Ks + row * 256 + ((kk * 64 + lk * 16) ^ ((row & 7) << 4)));
  }
  asm volatile("s_waitcnt lgkmcnt(0)" ::: "memory");
  __builtin_amdgcn_sched_barrier(0);

  float mrun[4], lrun[4];
  f32x4 Oacc[8] = {};
#pragma unroll
  for (int r = 0; r < 4; ++r) { mrun[r] = -1e30f; lrun[r] = 0.f; }
  const float scale = 0.08838834764831845f;

  for (int kt = 0; kt <= qt; ++kt) {
    __builtin_amdgcn_s_barrier();  // previous tile's LDS reads all consumed

    // stage K tile (64 x 256B)
#pragma unroll
    for (int o = 0; o < 4; ++o) {
      const int X = Xw + o * 1024 + lane * 16;
      const int r = X >> 8, Y = X & 255;
      const int cb = Y ^ ((r & 7) << 4);
      gload_lds16(qkv_b + (size_t)(kt * 64 + r) * (NQKV_ * 2) + HID_ * 2 + cb,
                  Ks + Xw + o * 1024);
    }
    // stage Vt tile (128 x 128B)
#pragma unroll
    for (int o = 0; o < 4; ++o) {
      const int X = Xw + o * 1024 + lane * 16;
      const int d = X >> 7, Y = X & 127;
      const int cb = Y ^ ((d & 7) << 4);
      gload_lds16(vt_b + (size_t)d * (S_ * 2) + kt * 128 + cb,
                  Vts + Xw + o * 1024);
    }
    asm volatile("s_waitcnt vmcnt(0)" ::: "memory");
    __builtin_amdgcn_s_barrier();
    __builtin_amdgcn_sched_barrier(0);

    // QK^T: A = Q rows, B = K^T (16 MFMAs)
    f32x4 sc[4];
#pragma unroll
    for (int cf = 0; cf < 4; ++cf) {
      f32x4 s = {0.f, 0.f, 0.f, 0.f};
      const int row = cf * 16 + lrow;
#pragma unroll
      for (int kk = 0; kk < 4; ++kk) {
        const bf16x8 kf = *(const bf16x8*)(Ks + row * 256 + ((kk * 64 + lk * 16) ^ ((row & 7) << 4)));
        s = __builtin_amdgcn_mfma_f32_16x16x32_bf16(qf[kk], kf, s, 0, 0, 0);
      }
      sc[cf] = s;
    }

    const bool diag = (kt == qt);
#pragma unroll
    for (int cf = 0; cf < 4; ++cf)
#pragma unroll
      for (int r = 0; r < 4; ++r) {
        float v = sc[cf][r] * scale;
        if (diag && (cf * 16 + lrow > wave * 16 + lk * 4 + r)) v = -1e30f;
        sc[cf][r] = v;
      }

    // online softmax (wave-parallel: shfl butterfly over 16-lane column groups)
    float corr[4];
#pragma unroll
    for (int r = 0; r < 4; ++r) {
      float mv = fmaxf(fmaxf(sc[0][r], sc[1][r]), fmaxf(sc[2][r], sc[3][r]));
#pragma unroll
      for (int xm = 1; xm < 16; xm <<= 1) mv = fmaxf(mv, __shfl_xor(mv, xm, 64));
      const float mn = fmaxf(mrun[r], mv);
      corr[r] = __expf(mrun[r] - mn);
      mrun[r] = mn;
    }
    float rsum[4] = {0.f, 0.f, 0.f, 0.f};
#pragma unroll
    for (int cf = 0; cf < 4; ++cf)
#pragma unroll
      for (int r = 0; r < 4; ++r) {
        const float p = __expf(sc[cf][r] - mrun[r]);
        sc[cf][r] = p;
        rsum[r] += p;
      }
#pragma unroll
    for (int r = 0; r < 4; ++r) {
#pragma unroll
      for (int xm = 1; xm < 16; xm <<= 1) rsum[r] += __shfl_xor(rsum[r], xm, 64);
      lrun[r] = lrun[r] * corr[r] + rsum[r];
    }
#pragma unroll
    for (int f = 0; f < 8; ++f)
#pragma unroll
      for (int r = 0; r < 4; ++r) Oacc[f][r] *= corr[r];

    // P -> per-wave LDS (bf16, swizzled)
#pragma unroll
    for (int cf = 0; cf < 4; ++cf)
#pragma unroll
      for (int r = 0; r < 4; ++r) {
        const int prow = lk * 4 + r;
        const int byte = prow * 128 + (((cf * 16 + lrow) * 2) ^ ((prow & 7) << 4));
        *(bf16*)(Ps + byte) = __float2bfloat16(sc[cf][r]);
      }
    asm volatile("s_waitcnt lgkmcnt(0)" ::: "memory");
    __builtin_amdgcn_sched_barrier(0);

    bf16x8 pf[2];
#pragma unroll
    for (int ks = 0; ks < 2; ++ks)
      pf[ks] = *(const bf16x8*)(Ps + lrow * 128 + ((ks * 64 + lk * 16) ^ ((lrow & 7) << 4)));

    // PV: A = P rows, B = Vt rows as V columns (16 MFMAs)
#pragma unroll
    for (int f = 0; f < 8; ++f) {
      const int d = f * 16 + lrow;
#pragma unroll
      for (int ks = 0; ks < 2; ++ks) {
        const bf16x8 vf = *(const bf16x8*)(Vts + d * 128 + ((ks * 64 + lk * 16) ^ ((d & 7) << 4)));
        Oacc[f] = __builtin_amdgcn_mfma_f32_16x16x32_bf16(pf[ks], vf, Oacc[f], 0, 0, 0);
      }
    }
  }

  // epilogue
#pragma unroll
  for (int f = 0; f < 8; ++f)
#pragma unroll
    for (int r = 0; r < 4; ++r) {
      const int token = b * S_ + qt * 64 + wave * 16 + lk * 4 + r;
      const int col = h * D_ + f * 16 + lrow;
      aout[(size_t)token * HID_ + col] = __float2bfloat16(Oacc[f][r] / lrun[r]);
    }
}

extern "C" void kernel_launch(void* const* d_in, const int* in_sizes, int n_in,
                              void* d_out, int out_size, void* d_ws, size_t ws_size,
                              hipStream_t stream) {
  const float* hidden = (const float*)d_in[0];
  const float* w_attn = (const float*)d_in[1];
  const float* b_attn = (const float*)d_in[2];
  const float* w_proj = (const float*)d_in[3];
  const float* b_proj = (const float*)d_in[4];

  char* ws = (char*)d_ws;
  char* dob = (char*)d_out;

  // ws: [0,33.5M) Xbf (bf16 hidden, later attn out); [33.5M,42M) WpT
  bf16* Xbf = (bf16*)ws;
  bf16* WpT = (bf16*)(ws + 33554432);
  // d_out as scratch (fully overwritten by GEMM2):
  // [0,37.75M) QKV bf16; [37.75M,47.2M) WaT; [48M,50M) Vt bf16
  bf16* QKV = (bf16*)dob;
  bf16* WaT = (bf16*)(dob + 37748736);
  bf16* Vt = (bf16*)(dob + 50331648);

  cast_bf16_kernel<<<(T_ * HID_) / 8 / 256, 256, 0, stream>>>(hidden, Xbf, (T_ * HID_) / 8);
  transpose_cast_kernel<<<dim3(NQKV_ / 32, HID_ / 32), 256, 0, stream>>>(w_attn, WaT, HID_, NQKV_);
  transpose_cast_kernel<<<dim3(HID_ / 32, HID_ / 32), 256, 0, stream>>>(w_proj, WpT, HID_, HID_);

  gemm_kernel<false><<<dim3(NQKV_ / 128, T_ / 128), 256, 0, stream>>>(
      Xbf, WaT, b_attn, QKV, T_, NQKV_, HID_);

  transpose_v_kernel<<<dim3(S_ / 64, D_ / 64, B_), 256, 0, stream>>>(QKV, Vt);

  attn_kernel<<<dim3(S_ / 64, H_, B_), 256, 0, stream>>>(QKV, Vt, Xbf);

  gemm_kernel<true><<<dim3(HID_ / 128, T_ / 128), 256, 0, stream>>>(
      Xbf, WpT, b_proj, (float*)d_out, T_, HID_, HID_);
}